// Round 5
// baseline (16769.789 us; speedup 1.0000x reference)
//
#include <hip/hip_runtime.h>

#define NXg 512
#define NYg 512
#define NNg (NXg*NYg)
#define TPB 256
#define NBT 512            // total blocks; __launch_bounds__(256,2) guarantees co-residency
#define NBC 128            // blocks per channel
#define NSTEPS 8
#define CGIT 10
#define DTf (1.0f/64.0f)
#define H2I 256.0f         // 1/h^2

// ws layout (floats):
//  [0]              ggen (int)
//  [16 + b*16]      per-block flags, b<512 (ints, 64B apart)
//  [12288..12800)   partA  [4][NBC]
//  [12800..13312)   partB  [4][NBC]
//  [16384 ..)       X | R | P0 | P1 planes (4*NNg each)
#define CTRL_FLOATS 16384

__device__ __forceinline__ int aload_acq(int* p){
  return __hip_atomic_load(p, __ATOMIC_ACQUIRE, __HIP_MEMORY_SCOPE_AGENT);
}
__device__ __forceinline__ void astore_rel(int* p, int v){
  __hip_atomic_store(p, v, __ATOMIC_RELEASE, __HIP_MEMORY_SCOPE_AGENT);
}

// tree-flag grid barrier: per-block flag stores (no serialized RMW),
// block 0 wave polls 512 flags, releases generation scalar.
__device__ __forceinline__ void gsync(int* wsi, int bid, int tid, int tgt){
  __syncthreads();
  if (tid==0){ __threadfence(); astore_rel(&wsi[16+bid*16], tgt); }
  if (bid==0 && tid<64){
    int ok=0;
    while(!ok){
      int m=1;
      #pragma unroll
      for (int j=0;j<8;++j)
        m &= (aload_acq(&wsi[16+(tid+j*64)*16]) >= tgt);
      ok=__all(m);
      if(!ok) __builtin_amdgcn_s_sleep(1);
    }
    __threadfence();
    if (tid==0) astore_rel(&wsi[0], tgt);
  }
  if (tid==0){
    while(aload_acq(&wsi[0])<tgt) __builtin_amdgcn_s_sleep(2);
    __threadfence();
  }
  __syncthreads();
}

// deterministic block-wide sum, identical result in all threads
__device__ __forceinline__ float block_sum(float v, float* lds) {
  #pragma unroll
  for (int off = 32; off > 0; off >>= 1) v += __shfl_down(v, off, 64);
  const int lane = threadIdx.x & 63;
  const int w    = threadIdx.x >> 6;
  if (lane == 0) lds[w] = v;
  __syncthreads();
  float s = (lds[0] + lds[1]) + (lds[2] + lds[3]);
  __syncthreads();
  return s;
}

__global__ void __launch_bounds__(TPB, 2)
dr_sw(const float* __restrict__ U0, const float* __restrict__ scale,
      const float* __restrict__ K1, const float* __restrict__ K2,
      const float* __restrict__ K3, float* __restrict__ out,
      float* __restrict__ ws)
{
  __shared__ float lds[4];
  __shared__ float sW[384];   // K1(64) | K2(256) | K3(64)

  for (int i = threadIdx.x; i < 384; i += TPB) {
    float w;
    if (i < 64)       w = K1[i];
    else if (i < 320) w = K2[i - 64];
    else              w = K3[i - 320];
    sW[i] = w;
  }

  int*   wsi   = (int*)ws;
  float* partA = ws + 12288;        // [4][NBC] pAp partials
  float* partB = ws + 12800;        // [4][NBC] r.r partials
  float* X  = ws + CTRL_FLOATS;     // 4 planes: current U / CG solution
  float* R  = X  + 4*NNg;           // 4 planes: residual mirror (halo)
  float* P0 = R  + 4*NNg;           // 4 planes: p buffer A
  float* P1 = P0 + 4*NNg;           // 4 planes: p buffer B

  const int bid = blockIdx.x, tid = threadIdx.x;
  const int ch  = bid >> 7;            // channel 0..3
  const int blk = bid & 127;           // block within channel
  const int row = blk*4 + (tid >> 6);  // 4 rows per block
  const int col = (tid & 63) << 3;     // 8 cells per thread
  const int idx = row*NXg + col;
  const bool hasUp = (row > 0), hasDn = (row < NYg-1);
  const bool hasL  = (col > 0), hasR  = (col + 8 < NXg);
  const float gamma = 1.0f / (scale[ch] * DTf);   // matches reference bit-for-bit

  float* Xc = X + ch*NNg;
  float* Rc = R + ch*NNg;
  float* PbufA = P0 + ch*NNg;
  float* PbufB = P1 + ch*NNg;
  float* pA = partA + ch*NBC;
  float* pB = partB + ch*NBC;

  int gen = 0;
  const int g2 = bid*TPB + tid;   // 0..131071 — flat mapping for deinterleave/MLP

  // de-interleave U0 (N,4) -> channel planes (2 cells per thread)
  #pragma unroll
  for (int c = 0; c < 2; ++c) {
    const int cell = g2 + c*(NNg/2);
    const float4 u = ((const float4*)U0)[cell];
    X[cell] = u.x; X[NNg+cell] = u.y; X[2*NNg+cell] = u.z; X[3*NNg+cell] = u.w;
  }
  gsync(wsi, bid, tid, ++gen);

  for (int step = 0; step < NSTEPS; ++step) {
    // ---- CG init: b = gamma*u, x0 = 0, r = b, rs = r.r ----
    float rr[8], xx[8], pold[8];
    {
      const float4 a = *(const float4*)(Xc + idx);
      const float4 b = *(const float4*)(Xc + idx + 4);
      rr[0]=gamma*a.x; rr[1]=gamma*a.y; rr[2]=gamma*a.z; rr[3]=gamma*a.w;
      rr[4]=gamma*b.x; rr[5]=gamma*b.y; rr[6]=gamma*b.z; rr[7]=gamma*b.w;
      #pragma unroll
      for (int k = 0; k < 8; ++k) { xx[k] = 0.f; pold[k] = 0.f; }
      *(float4*)(Rc + idx)     = make_float4(rr[0],rr[1],rr[2],rr[3]);
      *(float4*)(Rc + idx + 4) = make_float4(rr[4],rr[5],rr[6],rr[7]);
      // zero the it=0 "p_old" plane so halo reads are NaN-safe (ws is poisoned)
      *(float4*)(PbufB + idx)     = make_float4(0.f,0.f,0.f,0.f);
      *(float4*)(PbufB + idx + 4) = make_float4(0.f,0.f,0.f,0.f);
      float p = 0.f;
      #pragma unroll
      for (int k = 0; k < 8; ++k) p += rr[k]*rr[k];
      float bs = block_sum(p, lds);
      if (tid == 0) pB[blk] = bs;
    }
    gsync(wsi, bid, tid, ++gen);
    float rs = block_sum((tid < NBC) ? pB[tid] : 0.f, lds);
    float beta = 0.0f;
    float* Pcur = PbufA;
    float* Pold = PbufB;

    for (int it = 0; it < CGIT; ++it) {
      // phase A: p_new = r + beta*p_old (halo recomputed); Ap = A p_new; pAp
      float pn[8], Ap[8];
      #pragma unroll
      for (int k = 0; k < 8; ++k) pn[k] = rr[k] + beta*pold[k];
      if (it < CGIT-1) {  // last iteration's p is never read
        *(float4*)(Pcur + idx)     = make_float4(pn[0],pn[1],pn[2],pn[3]);
        *(float4*)(Pcur + idx + 4) = make_float4(pn[4],pn[5],pn[6],pn[7]);
      }

      float up[8], dn[8];
      #pragma unroll
      for (int k = 0; k < 8; ++k) { up[k] = 0.f; dn[k] = 0.f; }
      if (hasUp) {
        const float4 r0 = *(const float4*)(Rc + idx - NXg);
        const float4 r1 = *(const float4*)(Rc + idx - NXg + 4);
        const float4 p0 = *(const float4*)(Pold + idx - NXg);
        const float4 p1 = *(const float4*)(Pold + idx - NXg + 4);
        up[0]=r0.x+beta*p0.x; up[1]=r0.y+beta*p0.y; up[2]=r0.z+beta*p0.z; up[3]=r0.w+beta*p0.w;
        up[4]=r1.x+beta*p1.x; up[5]=r1.y+beta*p1.y; up[6]=r1.z+beta*p1.z; up[7]=r1.w+beta*p1.w;
      }
      if (hasDn) {
        const float4 r0 = *(const float4*)(Rc + idx + NXg);
        const float4 r1 = *(const float4*)(Rc + idx + NXg + 4);
        const float4 p0 = *(const float4*)(Pold + idx + NXg);
        const float4 p1 = *(const float4*)(Pold + idx + NXg + 4);
        dn[0]=r0.x+beta*p0.x; dn[1]=r0.y+beta*p0.y; dn[2]=r0.z+beta*p0.z; dn[3]=r0.w+beta*p0.w;
        dn[4]=r1.x+beta*p1.x; dn[5]=r1.y+beta*p1.y; dn[6]=r1.z+beta*p1.z; dn[7]=r1.w+beta*p1.w;
      }
      float lv = 0.f, rv = 0.f;
      if (hasL) lv = Rc[idx-1] + beta*Pold[idx-1];
      if (hasR) rv = Rc[idx+8] + beta*Pold[idx+8];

      float pAp = 0.f;
      #pragma unroll
      for (int k = 0; k < 8; ++k) {
        const float u = pn[k];
        float s = 0.f;
        if (hasUp) s += u - up[k];
        if (hasDn) s += u - dn[k];
        const float Lv = (k > 0) ? pn[k-1] : lv;
        if (k > 0 || hasL) s += u - Lv;
        const float Rv = (k < 7) ? pn[k+1] : rv;
        if (k < 7 || hasR) s += u - Rv;
        Ap[k] = s*H2I + gamma*u;
        pAp += u*Ap[k];
      }
      float bs = block_sum(pAp, lds);
      if (tid == 0) pA[blk] = bs;
      gsync(wsi, bid, tid, ++gen);   // sync 1
      const float pApT = block_sum((tid < NBC) ? pA[tid] : 0.f, lds);
      const float alpha = rs / pApT;
      #pragma unroll
      for (int k = 0; k < 8; ++k) { xx[k] += alpha*pn[k]; rr[k] -= alpha*Ap[k]; }

      if (it < CGIT-1) {
        // phase B: publish r, reduce r.r
        *(float4*)(Rc + idx)     = make_float4(rr[0],rr[1],rr[2],rr[3]);
        *(float4*)(Rc + idx + 4) = make_float4(rr[4],rr[5],rr[6],rr[7]);
        float rp = 0.f;
        #pragma unroll
        for (int k = 0; k < 8; ++k) rp += rr[k]*rr[k];
        float bs2 = block_sum(rp, lds);
        if (tid == 0) pB[blk] = bs2;
        gsync(wsi, bid, tid, ++gen); // sync 2
        const float rsn = block_sum((tid < NBC) ? pB[tid] : 0.f, lds);
        beta = rsn / rs;
        rs = rsn;
        #pragma unroll
        for (int k = 0; k < 8; ++k) pold[k] = pn[k];
        float* t = Pcur; Pcur = Pold; Pold = t;
      }
    }
    // publish solution
    *(float4*)(Xc + idx)     = make_float4(xx[0],xx[1],xx[2],xx[3]);
    *(float4*)(Xc + idx + 4) = make_float4(xx[4],xx[5],xx[6],xx[7]);
    gsync(wsi, bid, tid, ++gen);

    // ---- reaction: U += DT * tanh(tanh(tanh(U K1) K2) K3), flat mapping ----
    #pragma unroll
    for (int c = 0; c < 2; ++c) {
      const int cell = g2 + c*(NNg/2);
      float v0 = X[cell], v1 = X[NNg+cell], v2 = X[2*NNg+cell], v3 = X[3*NNg+cell];
      float h1[16], h2[16];
      #pragma unroll
      for (int h = 0; h < 16; ++h)
        h1[h] = tanhf(v0*sW[h] + v1*sW[16+h] + v2*sW[32+h] + v3*sW[48+h]);
      #pragma unroll
      for (int j = 0; j < 16; ++j) {
        float s = 0.f;
        #pragma unroll
        for (int h = 0; h < 16; ++h) s += h1[h]*sW[64 + 16*h + j];
        h2[j] = tanhf(s);
      }
      float o0=0.f,o1=0.f,o2=0.f,o3=0.f;
      #pragma unroll
      for (int j = 0; j < 16; ++j) {
        const float t = h2[j];
        o0 += t*sW[320 + 4*j + 0];
        o1 += t*sW[320 + 4*j + 1];
        o2 += t*sW[320 + 4*j + 2];
        o3 += t*sW[320 + 4*j + 3];
      }
      v0 += DTf*tanhf(o0); v1 += DTf*tanhf(o1);
      v2 += DTf*tanhf(o2); v3 += DTf*tanhf(o3);
      X[cell]=v0; X[NNg+cell]=v1; X[2*NNg+cell]=v2; X[3*NNg+cell]=v3;
      if (step == NSTEPS-1)
        ((float4*)out)[cell] = make_float4(v0, v1, v2, v3);
    }
    if (step < NSTEPS-1) gsync(wsi, bid, tid, ++gen);
  }
}

// diagnostic: runs ONLY if ws is too small — absmax ≈ 54321 signals that.
__global__ void diag_ws(float* out){ out[0] = 54321.0f; }

extern "C" void kernel_launch(void* const* d_in, const int* in_sizes, int n_in,
                              void* d_out, int out_size, void* d_ws, size_t ws_size,
                              hipStream_t stream) {
  const float* U0    = (const float*)d_in[0];
  const float* scale = (const float*)d_in[1];
  const float* K1    = (const float*)d_in[2];
  const float* K2    = (const float*)d_in[3];
  const float* K3    = (const float*)d_in[4];
  float* out = (float*)d_out;
  float* ws  = (float*)d_ws;

  const size_t need = (size_t)(CTRL_FLOATS + 16*NNg) * sizeof(float);
  if (ws_size < need) {
    hipLaunchKernelGGL(diag_ws, dim3(1), dim3(1), 0, stream, out);
    return;
  }
  // zero barrier flags + generation (harness poisons ws with 0xAA before timing)
  hipMemsetAsync(ws, 0, CTRL_FLOATS*sizeof(float), stream);
  hipLaunchKernelGGL(dr_sw, dim3(NBT), dim3(TPB), 0, stream,
                     U0, scale, K1, K2, K3, out, ws);
}

// Round 6
// 4552.543 us; speedup vs baseline: 3.6836x; 3.6836x over previous
//
#include <hip/hip_runtime.h>

#define NXg 512
#define NYg 512
#define NNg (NXg*NYg)
#define TPB 256
#define NBT 512            // total blocks; __launch_bounds__(256,2) guarantees co-residency
#define NBC 128            // blocks per channel
#define NSTEPS 8
#define CGIT 10
#define DTf (1.0f/64.0f)
#define H2I 256.0f         // 1/h^2

// ws layout (floats):
//  [0]              ggen (int)
//  [16 + b*16]      per-block flags, b<512 (ints, 64B apart)
//  [12288..12800)   partA  [4][NBC]
//  [12800..13312)   partB  [4][NBC]
//  [16384 ..)       X | R | P0 | P1 planes (4*NNg each)
#define CTRL_FLOATS 16384

// RELAXED spin loads — acquire-loads at agent scope emit cache invalidations
// every iteration (round-5 regression: 512 spinners thrashed all caches).
// Pay the fence ONCE after the spin exits instead.
__device__ __forceinline__ int aload_rlx(int* p){
  return __hip_atomic_load(p, __ATOMIC_RELAXED, __HIP_MEMORY_SCOPE_AGENT);
}
__device__ __forceinline__ void astore_rlx(int* p, int v){
  __hip_atomic_store(p, v, __ATOMIC_RELAXED, __HIP_MEMORY_SCOPE_AGENT);
}

// tree-flag grid barrier: per-block flag stores (no serialized RMW),
// block 0 wave polls 512 flags with relaxed loads, releases generation scalar.
__device__ __forceinline__ void gsync(int* wsi, int bid, int tid, int tgt){
  __syncthreads();
  if (tid==0){ __threadfence(); astore_rlx(&wsi[16+bid*16], tgt); }
  if (bid==0 && tid<64){
    int ok=0;
    while(!ok){
      int m=1;
      #pragma unroll
      for (int j=0;j<8;++j)
        m &= (aload_rlx(&wsi[16+(tid+j*64)*16]) >= tgt);
      ok=__all(m);
      if(!ok) __builtin_amdgcn_s_sleep(1);
    }
    if (tid==0){ __threadfence(); astore_rlx(&wsi[0], tgt); }
  }
  if (tid==0){
    while(aload_rlx(&wsi[0])<tgt) __builtin_amdgcn_s_sleep(2);
    __threadfence();   // single acquire-equivalent after spin exit
  }
  __syncthreads();
}

// deterministic block-wide sum, identical result in all threads
__device__ __forceinline__ float block_sum(float v, float* lds) {
  #pragma unroll
  for (int off = 32; off > 0; off >>= 1) v += __shfl_down(v, off, 64);
  const int lane = threadIdx.x & 63;
  const int w    = threadIdx.x >> 6;
  if (lane == 0) lds[w] = v;
  __syncthreads();
  float s = (lds[0] + lds[1]) + (lds[2] + lds[3]);
  __syncthreads();
  return s;
}

__global__ void __launch_bounds__(TPB, 2)
dr_sw(const float* __restrict__ U0, const float* __restrict__ scale,
      const float* __restrict__ K1, const float* __restrict__ K2,
      const float* __restrict__ K3, float* __restrict__ out,
      float* __restrict__ ws)
{
  __shared__ float lds[4];
  __shared__ float sW[384];   // K1(64) | K2(256) | K3(64)

  for (int i = threadIdx.x; i < 384; i += TPB) {
    float w;
    if (i < 64)       w = K1[i];
    else if (i < 320) w = K2[i - 64];
    else              w = K3[i - 320];
    sW[i] = w;
  }

  int*   wsi   = (int*)ws;
  float* partA = ws + 12288;        // [4][NBC] pAp partials
  float* partB = ws + 12800;        // [4][NBC] r.r partials
  float* X  = ws + CTRL_FLOATS;     // 4 planes: current U / CG solution
  float* R  = X  + 4*NNg;           // 4 planes: residual mirror (halo)
  float* P0 = R  + 4*NNg;           // 4 planes: p buffer A
  float* P1 = P0 + 4*NNg;           // 4 planes: p buffer B

  const int bid = blockIdx.x, tid = threadIdx.x;
  const int ch  = bid >> 7;            // channel 0..3
  const int blk = bid & 127;           // block within channel
  const int row = blk*4 + (tid >> 6);  // 4 rows per block
  const int col = (tid & 63) << 3;     // 8 cells per thread
  const int idx = row*NXg + col;
  const bool hasUp = (row > 0), hasDn = (row < NYg-1);
  const bool hasL  = (col > 0), hasR  = (col + 8 < NXg);
  const float gamma = 1.0f / (scale[ch] * DTf);   // matches reference bit-for-bit

  float* Xc = X + ch*NNg;
  float* Rc = R + ch*NNg;
  float* PbufA = P0 + ch*NNg;
  float* PbufB = P1 + ch*NNg;
  float* pA = partA + ch*NBC;
  float* pB = partB + ch*NBC;

  int gen = 0;
  const int g2 = bid*TPB + tid;   // 0..131071 — flat mapping for deinterleave/MLP

  // de-interleave U0 (N,4) -> channel planes (2 cells per thread)
  #pragma unroll
  for (int c = 0; c < 2; ++c) {
    const int cell = g2 + c*(NNg/2);
    const float4 u = ((const float4*)U0)[cell];
    X[cell] = u.x; X[NNg+cell] = u.y; X[2*NNg+cell] = u.z; X[3*NNg+cell] = u.w;
  }
  gsync(wsi, bid, tid, ++gen);

  for (int step = 0; step < NSTEPS; ++step) {
    // ---- CG init: b = gamma*u, x0 = 0, r = b, rs = r.r ----
    float rr[8], xx[8], pold[8];
    {
      const float4 a = *(const float4*)(Xc + idx);
      const float4 b = *(const float4*)(Xc + idx + 4);
      rr[0]=gamma*a.x; rr[1]=gamma*a.y; rr[2]=gamma*a.z; rr[3]=gamma*a.w;
      rr[4]=gamma*b.x; rr[5]=gamma*b.y; rr[6]=gamma*b.z; rr[7]=gamma*b.w;
      #pragma unroll
      for (int k = 0; k < 8; ++k) { xx[k] = 0.f; pold[k] = 0.f; }
      *(float4*)(Rc + idx)     = make_float4(rr[0],rr[1],rr[2],rr[3]);
      *(float4*)(Rc + idx + 4) = make_float4(rr[4],rr[5],rr[6],rr[7]);
      // zero the it=0 "p_old" plane so halo reads are NaN-safe (ws is poisoned)
      *(float4*)(PbufB + idx)     = make_float4(0.f,0.f,0.f,0.f);
      *(float4*)(PbufB + idx + 4) = make_float4(0.f,0.f,0.f,0.f);
      float p = 0.f;
      #pragma unroll
      for (int k = 0; k < 8; ++k) p += rr[k]*rr[k];
      float bs = block_sum(p, lds);
      if (tid == 0) pB[blk] = bs;
    }
    gsync(wsi, bid, tid, ++gen);
    float rs = block_sum((tid < NBC) ? pB[tid] : 0.f, lds);
    float beta = 0.0f;
    float* Pcur = PbufA;
    float* Pold = PbufB;

    for (int it = 0; it < CGIT; ++it) {
      // phase A: p_new = r + beta*p_old (halo recomputed); Ap = A p_new; pAp
      float pn[8], Ap[8];
      #pragma unroll
      for (int k = 0; k < 8; ++k) pn[k] = rr[k] + beta*pold[k];
      if (it < CGIT-1) {  // last iteration's p is never read
        *(float4*)(Pcur + idx)     = make_float4(pn[0],pn[1],pn[2],pn[3]);
        *(float4*)(Pcur + idx + 4) = make_float4(pn[4],pn[5],pn[6],pn[7]);
      }

      float up[8], dn[8];
      #pragma unroll
      for (int k = 0; k < 8; ++k) { up[k] = 0.f; dn[k] = 0.f; }
      if (hasUp) {
        const float4 r0 = *(const float4*)(Rc + idx - NXg);
        const float4 r1 = *(const float4*)(Rc + idx - NXg + 4);
        const float4 p0 = *(const float4*)(Pold + idx - NXg);
        const float4 p1 = *(const float4*)(Pold + idx - NXg + 4);
        up[0]=r0.x+beta*p0.x; up[1]=r0.y+beta*p0.y; up[2]=r0.z+beta*p0.z; up[3]=r0.w+beta*p0.w;
        up[4]=r1.x+beta*p1.x; up[5]=r1.y+beta*p1.y; up[6]=r1.z+beta*p1.z; up[7]=r1.w+beta*p1.w;
      }
      if (hasDn) {
        const float4 r0 = *(const float4*)(Rc + idx + NXg);
        const float4 r1 = *(const float4*)(Rc + idx + NXg + 4);
        const float4 p0 = *(const float4*)(Pold + idx + NXg);
        const float4 p1 = *(const float4*)(Pold + idx + NXg + 4);
        dn[0]=r0.x+beta*p0.x; dn[1]=r0.y+beta*p0.y; dn[2]=r0.z+beta*p0.z; dn[3]=r0.w+beta*p0.w;
        dn[4]=r1.x+beta*p1.x; dn[5]=r1.y+beta*p1.y; dn[6]=r1.z+beta*p1.z; dn[7]=r1.w+beta*p1.w;
      }
      float lv = 0.f, rv = 0.f;
      if (hasL) lv = Rc[idx-1] + beta*Pold[idx-1];
      if (hasR) rv = Rc[idx+8] + beta*Pold[idx+8];

      float pAp = 0.f;
      #pragma unroll
      for (int k = 0; k < 8; ++k) {
        const float u = pn[k];
        float s = 0.f;
        if (hasUp) s += u - up[k];
        if (hasDn) s += u - dn[k];
        const float Lv = (k > 0) ? pn[k-1] : lv;
        if (k > 0 || hasL) s += u - Lv;
        const float Rv = (k < 7) ? pn[k+1] : rv;
        if (k < 7 || hasR) s += u - Rv;
        Ap[k] = s*H2I + gamma*u;
        pAp += u*Ap[k];
      }
      float bs = block_sum(pAp, lds);
      if (tid == 0) pA[blk] = bs;
      gsync(wsi, bid, tid, ++gen);   // sync 1
      const float pApT = block_sum((tid < NBC) ? pA[tid] : 0.f, lds);
      const float alpha = rs / pApT;
      #pragma unroll
      for (int k = 0; k < 8; ++k) { xx[k] += alpha*pn[k]; rr[k] -= alpha*Ap[k]; }

      if (it < CGIT-1) {
        // phase B: publish r, reduce r.r
        *(float4*)(Rc + idx)     = make_float4(rr[0],rr[1],rr[2],rr[3]);
        *(float4*)(Rc + idx + 4) = make_float4(rr[4],rr[5],rr[6],rr[7]);
        float rp = 0.f;
        #pragma unroll
        for (int k = 0; k < 8; ++k) rp += rr[k]*rr[k];
        float bs2 = block_sum(rp, lds);
        if (tid == 0) pB[blk] = bs2;
        gsync(wsi, bid, tid, ++gen); // sync 2
        const float rsn = block_sum((tid < NBC) ? pB[tid] : 0.f, lds);
        beta = rsn / rs;
        rs = rsn;
        #pragma unroll
        for (int k = 0; k < 8; ++k) pold[k] = pn[k];
        float* t = Pcur; Pcur = Pold; Pold = t;
      }
    }
    // publish solution
    *(float4*)(Xc + idx)     = make_float4(xx[0],xx[1],xx[2],xx[3]);
    *(float4*)(Xc + idx + 4) = make_float4(xx[4],xx[5],xx[6],xx[7]);
    gsync(wsi, bid, tid, ++gen);

    // ---- reaction: U += DT * tanh(tanh(tanh(U K1) K2) K3), flat mapping ----
    #pragma unroll
    for (int c = 0; c < 2; ++c) {
      const int cell = g2 + c*(NNg/2);
      float v0 = X[cell], v1 = X[NNg+cell], v2 = X[2*NNg+cell], v3 = X[3*NNg+cell];
      float h1[16], h2[16];
      #pragma unroll
      for (int h = 0; h < 16; ++h)
        h1[h] = tanhf(v0*sW[h] + v1*sW[16+h] + v2*sW[32+h] + v3*sW[48+h]);
      #pragma unroll
      for (int j = 0; j < 16; ++j) {
        float s = 0.f;
        #pragma unroll
        for (int h = 0; h < 16; ++h) s += h1[h]*sW[64 + 16*h + j];
        h2[j] = tanhf(s);
      }
      float o0=0.f,o1=0.f,o2=0.f,o3=0.f;
      #pragma unroll
      for (int j = 0; j < 16; ++j) {
        const float t = h2[j];
        o0 += t*sW[320 + 4*j + 0];
        o1 += t*sW[320 + 4*j + 1];
        o2 += t*sW[320 + 4*j + 2];
        o3 += t*sW[320 + 4*j + 3];
      }
      v0 += DTf*tanhf(o0); v1 += DTf*tanhf(o1);
      v2 += DTf*tanhf(o2); v3 += DTf*tanhf(o3);
      X[cell]=v0; X[NNg+cell]=v1; X[2*NNg+cell]=v2; X[3*NNg+cell]=v3;
      if (step == NSTEPS-1)
        ((float4*)out)[cell] = make_float4(v0, v1, v2, v3);
    }
    if (step < NSTEPS-1) gsync(wsi, bid, tid, ++gen);
  }
}

// diagnostic: runs ONLY if ws is too small — absmax ≈ 54321 signals that.
__global__ void diag_ws(float* out){ out[0] = 54321.0f; }

extern "C" void kernel_launch(void* const* d_in, const int* in_sizes, int n_in,
                              void* d_out, int out_size, void* d_ws, size_t ws_size,
                              hipStream_t stream) {
  const float* U0    = (const float*)d_in[0];
  const float* scale = (const float*)d_in[1];
  const float* K1    = (const float*)d_in[2];
  const float* K2    = (const float*)d_in[3];
  const float* K3    = (const float*)d_in[4];
  float* out = (float*)d_out;
  float* ws  = (float*)d_ws;

  const size_t need = (size_t)(CTRL_FLOATS + 16*NNg) * sizeof(float);
  if (ws_size < need) {
    hipLaunchKernelGGL(diag_ws, dim3(1), dim3(1), 0, stream, out);
    return;
  }
  // zero barrier flags + generation (harness poisons ws with 0xAA before timing)
  hipMemsetAsync(ws, 0, CTRL_FLOATS*sizeof(float), stream);
  hipLaunchKernelGGL(dr_sw, dim3(NBT), dim3(TPB), 0, stream,
                     U0, scale, K1, K2, K3, out, ws);
}

// Round 9
// 4462.514 us; speedup vs baseline: 3.7579x; 1.0202x over previous
//
#include <hip/hip_runtime.h>

#define NXg 512
#define NYg 512
#define NNg (NXg*NYg)
#define TPB 256
#define NBT 512            // total blocks; __launch_bounds__(256,2) guarantees co-residency
#define NBC 128            // blocks per channel
#define NSTEPS 8
#define CGIT 10
#define DTf (1.0f/64.0f)
#define H2I 256.0f         // 1/h^2

// ws layout (floats):
//  [16 + b*16]      per-block arrival flags, b<512 (ints, 64B apart; last at 8192)
//  [9216 + l*16]    64 release lines, l<64 (ints)  -- contention fix (round 9)
//  [12288..12800)   partA  [4][NBC]
//  [12800..13312)   partB  [4][NBC]
//  [16384 ..)       X | R | P0 | P1 planes (4*NNg each)
#define CTRL_FLOATS 16384

// RELAXED spin loads — acquire-loads at agent scope emit cache invalidations
// every iteration (round-5 regression: cache thrash). Fence ONCE after spin.
__device__ __forceinline__ int aload_rlx(int* p){
  return __hip_atomic_load(p, __ATOMIC_RELAXED, __HIP_MEMORY_SCOPE_AGENT);
}
__device__ __forceinline__ void astore_rlx(int* p, int v){
  __hip_atomic_store(p, v, __ATOMIC_RELAXED, __HIP_MEMORY_SCOPE_AGENT);
}

// Tree-flag grid barrier (round-6 proven), with 64-line broadcast release:
// single-scalar release had 511 thread-0s hammering one LLC line (~25us/sync,
// serialized same-address reads). 64 lines -> 8 pollers/line.
__device__ __forceinline__ void gsync(int* wsi, int bid, int tid, int tgt){
  __syncthreads();
  if (tid==0){ __threadfence(); astore_rlx(&wsi[16+bid*16], tgt); }
  if (bid==0 && tid<64){
    int ok=0;
    while(!ok){
      int m=1;
      #pragma unroll
      for (int j=0;j<8;++j)
        m &= (aload_rlx(&wsi[16+(tid+j*64)*16]) >= tgt);
      ok=__all(m);
      if(!ok) __builtin_amdgcn_s_sleep(1);
    }
    // producers fenced before their flags; master only forwards the fact.
    astore_rlx(&wsi[9216 + tid*16], tgt);   // 64 release lines, one per lane
  }
  if (tid==0){
    int* rl = &wsi[9216 + (bid&63)*16];
    while(aload_rlx(rl)<tgt) __builtin_amdgcn_s_sleep(2);
    __threadfence();   // single consumer-side invalidate after spin exit
  }
  __syncthreads();
}

// deterministic block-wide sum, identical result in all threads
__device__ __forceinline__ float block_sum(float v, float* lds) {
  #pragma unroll
  for (int off = 32; off > 0; off >>= 1) v += __shfl_down(v, off, 64);
  const int lane = threadIdx.x & 63;
  const int w    = threadIdx.x >> 6;
  if (lane == 0) lds[w] = v;
  __syncthreads();
  float s = (lds[0] + lds[1]) + (lds[2] + lds[3]);
  __syncthreads();
  return s;
}

__global__ void __launch_bounds__(TPB, 2)
dr_sw(const float* __restrict__ U0, const float* __restrict__ scale,
      const float* __restrict__ K1, const float* __restrict__ K2,
      const float* __restrict__ K3, float* __restrict__ out,
      float* __restrict__ ws)
{
  __shared__ float lds[4];
  __shared__ float sW[384];   // K1(64) | K2(256) | K3(64)

  for (int i = threadIdx.x; i < 384; i += TPB) {
    float w;
    if (i < 64)       w = K1[i];
    else if (i < 320) w = K2[i - 64];
    else              w = K3[i - 320];
    sW[i] = w;
  }

  int*   wsi   = (int*)ws;
  float* partA = ws + 12288;        // [4][NBC] pAp partials
  float* partB = ws + 12800;        // [4][NBC] r.r partials
  float* X  = ws + CTRL_FLOATS;     // 4 planes: current U / CG solution
  float* R  = X  + 4*NNg;           // 4 planes: residual mirror (halo)
  float* P0 = R  + 4*NNg;           // 4 planes: p buffer A
  float* P1 = P0 + 4*NNg;           // 4 planes: p buffer B

  const int bid = blockIdx.x, tid = threadIdx.x;
  const int ch  = bid >> 7;            // channel 0..3
  const int blk = bid & 127;           // block within channel
  const int row = blk*4 + (tid >> 6);  // 4 rows per block
  const int col = (tid & 63) << 3;     // 8 cells per thread
  const int idx = row*NXg + col;
  const bool hasUp = (row > 0), hasDn = (row < NYg-1);
  const bool hasL  = (col > 0), hasR  = (col + 8 < NXg);
  const float gamma = 1.0f / (scale[ch] * DTf);   // matches reference bit-for-bit

  float* Xc = X + ch*NNg;
  float* Rc = R + ch*NNg;
  float* PbufA = P0 + ch*NNg;
  float* PbufB = P1 + ch*NNg;
  float* pA = partA + ch*NBC;
  float* pB = partB + ch*NBC;

  int gen = 0;
  const int g2 = bid*TPB + tid;   // 0..131071 — flat mapping for deinterleave/MLP

  // de-interleave U0 (N,4) -> channel planes (2 cells per thread)
  #pragma unroll
  for (int c = 0; c < 2; ++c) {
    const int cell = g2 + c*(NNg/2);
    const float4 u = ((const float4*)U0)[cell];
    X[cell] = u.x; X[NNg+cell] = u.y; X[2*NNg+cell] = u.z; X[3*NNg+cell] = u.w;
  }
  gsync(wsi, bid, tid, ++gen);

  for (int step = 0; step < NSTEPS; ++step) {
    // ---- CG init: b = gamma*u, x0 = 0, r = b, rs = r.r ----
    float rr[8], xx[8], pold[8];
    {
      const float4 a = *(const float4*)(Xc + idx);
      const float4 b = *(const float4*)(Xc + idx + 4);
      rr[0]=gamma*a.x; rr[1]=gamma*a.y; rr[2]=gamma*a.z; rr[3]=gamma*a.w;
      rr[4]=gamma*b.x; rr[5]=gamma*b.y; rr[6]=gamma*b.z; rr[7]=gamma*b.w;
      #pragma unroll
      for (int k = 0; k < 8; ++k) { xx[k] = 0.f; pold[k] = 0.f; }
      *(float4*)(Rc + idx)     = make_float4(rr[0],rr[1],rr[2],rr[3]);
      *(float4*)(Rc + idx + 4) = make_float4(rr[4],rr[5],rr[6],rr[7]);
      // zero the it=0 "p_old" plane so halo reads are NaN-safe (ws is poisoned)
      *(float4*)(PbufB + idx)     = make_float4(0.f,0.f,0.f,0.f);
      *(float4*)(PbufB + idx + 4) = make_float4(0.f,0.f,0.f,0.f);
      float p = 0.f;
      #pragma unroll
      for (int k = 0; k < 8; ++k) p += rr[k]*rr[k];
      float bs = block_sum(p, lds);
      if (tid == 0) pB[blk] = bs;
    }
    gsync(wsi, bid, tid, ++gen);
    float rs = block_sum((tid < NBC) ? pB[tid] : 0.f, lds);
    float beta = 0.0f;
    float* Pcur = PbufA;
    float* Pold = PbufB;

    for (int it = 0; it < CGIT; ++it) {
      // phase A: p_new = r + beta*p_old (halo recomputed); Ap = A p_new; pAp
      float pn[8], Ap[8];
      #pragma unroll
      for (int k = 0; k < 8; ++k) pn[k] = rr[k] + beta*pold[k];
      if (it < CGIT-1) {  // last iteration's p is never read
        *(float4*)(Pcur + idx)     = make_float4(pn[0],pn[1],pn[2],pn[3]);
        *(float4*)(Pcur + idx + 4) = make_float4(pn[4],pn[5],pn[6],pn[7]);
      }

      float up[8], dn[8];
      #pragma unroll
      for (int k = 0; k < 8; ++k) { up[k] = 0.f; dn[k] = 0.f; }
      if (hasUp) {
        const float4 r0 = *(const float4*)(Rc + idx - NXg);
        const float4 r1 = *(const float4*)(Rc + idx - NXg + 4);
        const float4 p0 = *(const float4*)(Pold + idx - NXg);
        const float4 p1 = *(const float4*)(Pold + idx - NXg + 4);
        up[0]=r0.x+beta*p0.x; up[1]=r0.y+beta*p0.y; up[2]=r0.z+beta*p0.z; up[3]=r0.w+beta*p0.w;
        up[4]=r1.x+beta*p1.x; up[5]=r1.y+beta*p1.y; up[6]=r1.z+beta*p1.z; up[7]=r1.w+beta*p1.w;
      }
      if (hasDn) {
        const float4 r0 = *(const float4*)(Rc + idx + NXg);
        const float4 r1 = *(const float4*)(Rc + idx + NXg + 4);
        const float4 p0 = *(const float4*)(Pold + idx + NXg);
        const float4 p1 = *(const float4*)(Pold + idx + NXg + 4);
        dn[0]=r0.x+beta*p0.x; dn[1]=r0.y+beta*p0.y; dn[2]=r0.z+beta*p0.z; dn[3]=r0.w+beta*p0.w;
        dn[4]=r1.x+beta*p1.x; dn[5]=r1.y+beta*p1.y; dn[6]=r1.z+beta*p1.z; dn[7]=r1.w+beta*p1.w;
      }
      float lv = 0.f, rv = 0.f;
      if (hasL) lv = Rc[idx-1] + beta*Pold[idx-1];
      if (hasR) rv = Rc[idx+8] + beta*Pold[idx+8];

      float pAp = 0.f;
      #pragma unroll
      for (int k = 0; k < 8; ++k) {
        const float u = pn[k];
        float s = 0.f;
        if (hasUp) s += u - up[k];
        if (hasDn) s += u - dn[k];
        const float Lv = (k > 0) ? pn[k-1] : lv;
        if (k > 0 || hasL) s += u - Lv;
        const float Rv = (k < 7) ? pn[k+1] : rv;
        if (k < 7 || hasR) s += u - Rv;
        Ap[k] = s*H2I + gamma*u;
        pAp += u*Ap[k];
      }
      float bs = block_sum(pAp, lds);
      if (tid == 0) pA[blk] = bs;
      gsync(wsi, bid, tid, ++gen);   // sync 1
      const float pApT = block_sum((tid < NBC) ? pA[tid] : 0.f, lds);
      const float alpha = rs / pApT;
      #pragma unroll
      for (int k = 0; k < 8; ++k) { xx[k] += alpha*pn[k]; rr[k] -= alpha*Ap[k]; }

      if (it < CGIT-1) {
        // phase B: publish r, reduce r.r
        *(float4*)(Rc + idx)     = make_float4(rr[0],rr[1],rr[2],rr[3]);
        *(float4*)(Rc + idx + 4) = make_float4(rr[4],rr[5],rr[6],rr[7]);
        float rp = 0.f;
        #pragma unroll
        for (int k = 0; k < 8; ++k) rp += rr[k]*rr[k];
        float bs2 = block_sum(rp, lds);
        if (tid == 0) pB[blk] = bs2;
        gsync(wsi, bid, tid, ++gen); // sync 2
        const float rsn = block_sum((tid < NBC) ? pB[tid] : 0.f, lds);
        beta = rsn / rs;
        rs = rsn;
        #pragma unroll
        for (int k = 0; k < 8; ++k) pold[k] = pn[k];
        float* t = Pcur; Pcur = Pold; Pold = t;
      }
    }
    // publish solution
    *(float4*)(Xc + idx)     = make_float4(xx[0],xx[1],xx[2],xx[3]);
    *(float4*)(Xc + idx + 4) = make_float4(xx[4],xx[5],xx[6],xx[7]);
    gsync(wsi, bid, tid, ++gen);

    // ---- reaction: U += DT * tanh(tanh(tanh(U K1) K2) K3), flat mapping ----
    #pragma unroll
    for (int c = 0; c < 2; ++c) {
      const int cell = g2 + c*(NNg/2);
      float v0 = X[cell], v1 = X[NNg+cell], v2 = X[2*NNg+cell], v3 = X[3*NNg+cell];
      float h1[16], h2[16];
      #pragma unroll
      for (int h = 0; h < 16; ++h)
        h1[h] = tanhf(v0*sW[h] + v1*sW[16+h] + v2*sW[32+h] + v3*sW[48+h]);
      #pragma unroll
      for (int j = 0; j < 16; ++j) {
        float s = 0.f;
        #pragma unroll
        for (int h = 0; h < 16; ++h) s += h1[h]*sW[64 + 16*h + j];
        h2[j] = tanhf(s);
      }
      float o0=0.f,o1=0.f,o2=0.f,o3=0.f;
      #pragma unroll
      for (int j = 0; j < 16; ++j) {
        const float t = h2[j];
        o0 += t*sW[320 + 4*j + 0];
        o1 += t*sW[320 + 4*j + 1];
        o2 += t*sW[320 + 4*j + 2];
        o3 += t*sW[320 + 4*j + 3];
      }
      v0 += DTf*tanhf(o0); v1 += DTf*tanhf(o1);
      v2 += DTf*tanhf(o2); v3 += DTf*tanhf(o3);
      X[cell]=v0; X[NNg+cell]=v1; X[2*NNg+cell]=v2; X[3*NNg+cell]=v3;
      if (step == NSTEPS-1)
        ((float4*)out)[cell] = make_float4(v0, v1, v2, v3);
    }
    if (step < NSTEPS-1) gsync(wsi, bid, tid, ++gen);
  }
}

// diagnostic: runs ONLY if ws is too small — absmax ≈ 54321 signals that.
__global__ void diag_ws(float* out){ out[0] = 54321.0f; }

extern "C" void kernel_launch(void* const* d_in, const int* in_sizes, int n_in,
                              void* d_out, int out_size, void* d_ws, size_t ws_size,
                              hipStream_t stream) {
  const float* U0    = (const float*)d_in[0];
  const float* scale = (const float*)d_in[1];
  const float* K1    = (const float*)d_in[2];
  const float* K2    = (const float*)d_in[3];
  const float* K3    = (const float*)d_in[4];
  float* out = (float*)d_out;
  float* ws  = (float*)d_ws;

  const size_t need = (size_t)(CTRL_FLOATS + 16*NNg) * sizeof(float);
  if (ws_size < need) {
    hipLaunchKernelGGL(diag_ws, dim3(1), dim3(1), 0, stream, out);
    return;
  }
  // zero barrier flags + release lines (harness poisons ws with 0xAA)
  hipMemsetAsync(ws, 0, CTRL_FLOATS*sizeof(float), stream);
  hipLaunchKernelGGL(dr_sw, dim3(NBT), dim3(TPB), 0, stream,
                     U0, scale, K1, K2, K3, out, ws);
}

// Round 11
// 2334.341 us; speedup vs baseline: 7.1839x; 1.9117x over previous
//
#include <hip/hip_runtime.h>

#define NXg 512
#define NYg 512
#define NNg (NXg*NYg)
#define TPB 512
#define NBT 256
#define NSTEPS 8
#define CGIT 10
#define DTf (1.0f/64.0f)
#define H2I 256.0f

// ws float layout — ALL cross-block traffic via relaxed AGENT (sc1) atomics.
// NO __threadfence anywhere (no buffer_wbl2/inv). Direct-Σr² CG (r9 math).
//  [b*16], b<256        arrival flags (int)
//  [4096 + l*16], l<64  release lines (int)
//  [8192 .. 16384)      parts[2 parity][16 metric][256 block]
//                       metrics: 0-3 pAp | 4-7 bb | 8-11 rsn
//  [16384 ..)           R[4ch][NNg] | P[2 par][4 ch][NNg]
#define REL_OFF     4096
#define PARTS_OFF   8192
#define CTRL_FLOATS 16384
#define R_OFF(c)      (CTRL_FLOATS + (c)*NNg)
#define P_OFF(par,c)  (CTRL_FLOATS + 4*NNg + ((par)*4+(c))*NNg)

__device__ __forceinline__ int ld_flag(int* p){
  return __hip_atomic_load(p, __ATOMIC_RELAXED, __HIP_MEMORY_SCOPE_AGENT);
}
__device__ __forceinline__ void st_flag(int* p, int v){
  __hip_atomic_store(p, v, __ATOMIC_RELAXED, __HIP_MEMORY_SCOPE_AGENT);
}
__device__ __forceinline__ float ldg1(float* p){
  return __hip_atomic_load(p, __ATOMIC_RELAXED, __HIP_MEMORY_SCOPE_AGENT);
}
__device__ __forceinline__ void stg1(float* p, float v){
  __hip_atomic_store(p, v, __ATOMIC_RELAXED, __HIP_MEMORY_SCOPE_AGENT);
}

// Fence-free barrier: vmcnt(0) drains this wave's sc1 stores (ack at the
// coherence point), barrier, flag store; block 0 polls 256 flags, then
// broadcasts over 64 release lines. Relaxed spins only (r5 lesson).
__device__ __forceinline__ void gsync(int* wsi, int bid, int tid, int tgt){
  asm volatile("s_waitcnt vmcnt(0)" ::: "memory");
  __syncthreads();
  if (tid==0) st_flag(&wsi[bid*16], tgt);
  if (bid==0 && tid<64){
    int ok=0;
    while(!ok){
      int m=1;
      #pragma unroll
      for (int j=0;j<4;++j) m &= (ld_flag(&wsi[(tid+64*j)*16]) >= tgt);
      ok=__all(m);
      if(!ok) __builtin_amdgcn_s_sleep(1);
    }
    st_flag(&wsi[REL_OFF + tid*16], tgt);
  }
  if (tid==0){
    int* rl = &wsi[REL_OFF + (bid&63)*16];
    while(ld_flag(rl) < tgt) __builtin_amdgcn_s_sleep(1);
  }
  __syncthreads();
}

__device__ __forceinline__ void mlp_all(const float* sW, const float* vv, float* o){
  float h1[16];
  #pragma unroll
  for (int h=0;h<16;++h)
    h1[h] = tanhf(vv[0]*sW[h]+vv[1]*sW[16+h]+vv[2]*sW[32+h]+vv[3]*sW[48+h]);
  o[0]=o[1]=o[2]=o[3]=0.f;
  #pragma unroll
  for (int j=0;j<16;++j){
    float s=0.f;
    #pragma unroll
    for (int h=0;h<16;++h) s += h1[h]*sW[64+16*h+j];
    const float t = tanhf(s);
    o[0]+=t*sW[320+4*j+0]; o[1]+=t*sW[320+4*j+1];
    o[2]+=t*sW[320+4*j+2]; o[3]+=t*sW[320+4*j+3];
  }
}

__global__ void __launch_bounds__(TPB)
drk(const float* __restrict__ U0, const float* __restrict__ scale,
    const float* __restrict__ K1, const float* __restrict__ K2,
    const float* __restrict__ K3, float* __restrict__ out,
    float* __restrict__ ws)
{
  __shared__ float sW[384];
  __shared__ float sP[2][4][NXg];   // pn tile, 16 KB
  __shared__ float wRed[8][8];
  __shared__ float sRed[12];

  const int tid=threadIdx.x, bid=blockIdx.x;
  const int r    = tid>>8;          // row in block: 0/1
  const int lane = tid&63;
  const int wv   = tid>>6;          // wave 0..7
  const int c2   = (tid&255)*2;     // column base (2 cells/thread)
  const int grow = bid*2 + r;
  const int cell0= grow*NXg + c2;
  const bool hUp = (r==0) && (grow>0);
  const bool hDn = (r==1) && (grow<NYg-1);
  const int hrow = (r==0) ? (grow-1) : (grow+1);

  if (tid < 384){
    float w;
    if (tid < 64)       w = K1[tid];
    else if (tid < 320) w = K2[tid-64];
    else                w = K3[tid-320];
    sW[tid]=w;
  }
  __syncthreads();

  int* wsi = (int*)ws;
  float gam[4];
  #pragma unroll
  for (int c=0;c<4;++c) gam[c] = 1.0f/(scale[c]*DTf);

  float xnew[2][4];
  {
    const float4 u0 = ((const float4*)U0)[cell0];
    const float4 u1 = ((const float4*)U0)[cell0+1];
    xnew[0][0]=u0.x; xnew[0][1]=u0.y; xnew[0][2]=u0.z; xnew[0][3]=u0.w;
    xnew[1][0]=u1.x; xnew[1][1]=u1.y; xnew[1][2]=u1.z; xnew[1][3]=u1.w;
  }

  for (int step=0; step<NSTEPS; ++step){
    float rr[2][4], xx[2][4], pold[2][4];
    float alpha[4], beta[4], rs[4], bb[4];
    #pragma unroll
    for (int c=0;c<4;++c){
      bb[c]=0.f; beta[c]=0.f;
      #pragma unroll
      for (int k=0;k<2;++k){
        rr[k][c] = gam[c]*xnew[k][c];
        bb[c]   += rr[k][c]*rr[k][c];
        xx[k][c]=0.f; pold[k][c]=0.f;
      }
    }

    for (int it=0; it<CGIT; ++it){
      const int g = step*CGIT + it;
      const int par = g&1;
      float* parts = ws + PARTS_OFF + par*4096;

      // ---- phase A: pn = r + beta*p_old; publish pn; halo pn recon ----
      float pn[2][4], Ap[2][4];
      #pragma unroll
      for (int k=0;k<2;++k)
      #pragma unroll
      for (int c=0;c<4;++c){
        pn[k][c] = rr[k][c] + beta[c]*pold[k][c];
        sP[r][c][c2+k] = pn[k][c];
      }
      #pragma unroll
      for (int c=0;c<4;++c){
        stg1(ws + P_OFF(par,c) + grow*NXg + c2,   pn[0][c]);
        stg1(ws + P_OFF(par,c) + grow*NXg + c2+1, pn[1][c]);
      }

      // halo pn = R_halo + beta*P_halo(prev parity). At it==0 beta==0.
      float pnh[2][4];
      #pragma unroll
      for (int k=0;k<2;++k)
      #pragma unroll
      for (int c=0;c<4;++c) pnh[k][c]=0.f;
      if (hUp || hDn){
        if (step==0 && it==0){
          // R not yet published: b = gamma*U0 read directly from input
          const float4 h0 = ((const float4*)U0)[hrow*NXg + c2];
          const float4 h1 = ((const float4*)U0)[hrow*NXg + c2+1];
          pnh[0][0]=gam[0]*h0.x; pnh[0][1]=gam[1]*h0.y; pnh[0][2]=gam[2]*h0.z; pnh[0][3]=gam[3]*h0.w;
          pnh[1][0]=gam[0]*h1.x; pnh[1][1]=gam[1]*h1.y; pnh[1][2]=gam[2]*h1.z; pnh[1][3]=gam[3]*h1.w;
        } else {
          #pragma unroll
          for (int c=0;c<4;++c){
            const float hr0 = ldg1(ws + R_OFF(c) + hrow*NXg + c2);
            const float hr1 = ldg1(ws + R_OFF(c) + hrow*NXg + c2+1);
            const float hp0 = ldg1(ws + P_OFF(par^1,c) + hrow*NXg + c2);
            const float hp1 = ldg1(ws + P_OFF(par^1,c) + hrow*NXg + c2+1);
            pnh[0][c] = hr0 + beta[c]*hp0;
            pnh[1][c] = hr1 + beta[c]*hp1;
          }
        }
      }
      __syncthreads();   // sP tile complete

      // ---- stencil + pAp partials ----
      float pap[4]={0,0,0,0};
      #pragma unroll
      for (int c=0;c<4;++c)
      #pragma unroll
      for (int k=0;k<2;++k){
        const int col = c2+k;
        const float u = pn[k][c];
        float s = 0.f;
        if (r==1) s += u - sP[0][c][col]; else if (grow>0)     s += u - pnh[k][c];
        if (r==0) s += u - sP[1][c][col]; else if (grow<NYg-1) s += u - pnh[k][c];
        if (col > 0)     s += u - ((k==1) ? pn[0][c] : sP[r][c][col-1]);
        if (col < NXg-1) s += u - ((k==0) ? pn[1][c] : sP[r][c][col+1]);
        const float ap = s*H2I + gam[c]*u;
        Ap[k][c] = ap;
        pap[c]  += u*ap;
      }

      // block-reduce 8 metrics {pAp[4], bb[4]} -> parts
      {
        float m8[8];
        #pragma unroll
        for (int c=0;c<4;++c){ m8[c]=pap[c]; m8[4+c]=bb[c]; }
        #pragma unroll
        for (int m=0;m<8;++m){
          float v=m8[m];
          #pragma unroll
          for (int off=32; off; off>>=1) v += __shfl_xor(v, off);
          m8[m]=v;
        }
        if (lane==0){
          #pragma unroll
          for (int m=0;m<8;++m) wRed[wv][m]=m8[m];
        }
        __syncthreads();
        if (tid<8){
          float s=0.f;
          #pragma unroll
          for (int w=0;w<8;++w) s += wRed[w][tid];
          stg1(parts + tid*256 + bid, s);
        }
      }
      gsync(wsi, bid, tid, 2*g+1);

      // all-to-all read: wave wv sums metric wv over 256 blocks
      {
        float s=0.f;
        #pragma unroll
        for (int j=0;j<4;++j) s += ldg1(parts + wv*256 + lane*4+j);
        #pragma unroll
        for (int off=32; off; off>>=1) s += __shfl_xor(s, off);
        if (lane==0) sRed[wv]=s;
      }
      __syncthreads();
      #pragma unroll
      for (int c=0;c<4;++c){
        if (it==0) rs[c] = sRed[4+c];
        alpha[c] = rs[c]/sRed[c];
      }
      #pragma unroll
      for (int k=0;k<2;++k)
      #pragma unroll
      for (int c=0;c<4;++c){
        xx[k][c] += alpha[c]*pn[k][c];
        rr[k][c] -= alpha[c]*Ap[k][c];
      }

      if (it < CGIT-1){
        // ---- phase B: publish r; DIRECT Σr² reduce (no recurrence!) ----
        float rp[4]={0,0,0,0};
        #pragma unroll
        for (int c=0;c<4;++c){
          stg1(ws + R_OFF(c) + grow*NXg + c2,   rr[0][c]);
          stg1(ws + R_OFF(c) + grow*NXg + c2+1, rr[1][c]);
          rp[c] = rr[0][c]*rr[0][c] + rr[1][c]*rr[1][c];
        }
        {
          float m4[4];
          #pragma unroll
          for (int c=0;c<4;++c) m4[c]=rp[c];
          #pragma unroll
          for (int m=0;m<4;++m){
            float v=m4[m];
            #pragma unroll
            for (int off=32; off; off>>=1) v += __shfl_xor(v, off);
            m4[m]=v;
          }
          if (lane==0){
            #pragma unroll
            for (int m=0;m<4;++m) wRed[wv][m]=m4[m];
          }
          __syncthreads();
          if (tid<4){
            float s=0.f;
            #pragma unroll
            for (int w=0;w<8;++w) s += wRed[w][tid];
            stg1(parts + (8+tid)*256 + bid, s);
          }
        }
        gsync(wsi, bid, tid, 2*g+2);
        if (wv<4){
          float s=0.f;
          #pragma unroll
          for (int j=0;j<4;++j) s += ldg1(parts + (8+wv)*256 + lane*4+j);
          #pragma unroll
          for (int off=32; off; off>>=1) s += __shfl_xor(s, off);
          if (lane==0) sRed[8+wv]=s;
        }
        __syncthreads();
        #pragma unroll
        for (int c=0;c<4;++c){
          const float rsn = sRed[8+c];
          beta[c] = rsn/rs[c];
          rs[c]   = rsn;
        }
        #pragma unroll
        for (int k=0;k<2;++k)
        #pragma unroll
        for (int c=0;c<4;++c) pold[k][c]=pn[k][c];
      } else {
        // ---- last iter: reaction (block-local), publish next b ----
        #pragma unroll
        for (int k=0;k<2;++k){
          float vv[4] = {xx[k][0], xx[k][1], xx[k][2], xx[k][3]};
          float o[4];
          mlp_all(sW, vv, o);
          #pragma unroll
          for (int c=0;c<4;++c) xnew[k][c] = xx[k][c] + DTf*tanhf(o[c]);
        }
        if (step < NSTEPS-1){
          #pragma unroll
          for (int c=0;c<4;++c){
            stg1(ws + R_OFF(c) + grow*NXg + c2,   gam[c]*xnew[0][c]);
            stg1(ws + R_OFF(c) + grow*NXg + c2+1, gam[c]*xnew[1][c]);
          }
          gsync(wsi, bid, tid, 2*g+2);   // step-boundary sync (folded)
        } else {
          ((float4*)out)[cell0]   = make_float4(xnew[0][0],xnew[0][1],xnew[0][2],xnew[0][3]);
          ((float4*)out)[cell0+1] = make_float4(xnew[1][0],xnew[1][1],xnew[1][2],xnew[1][3]);
        }
      }
    }
  }
}

// diagnostic: runs ONLY if ws is too small — absmax ≈ 54321 signals that.
__global__ void diag_ws(float* out){ out[0] = 54321.0f; }

extern "C" void kernel_launch(void* const* d_in, const int* in_sizes, int n_in,
                              void* d_out, int out_size, void* d_ws, size_t ws_size,
                              hipStream_t stream) {
  const float* U0    = (const float*)d_in[0];
  const float* scale = (const float*)d_in[1];
  const float* K1    = (const float*)d_in[2];
  const float* K2    = (const float*)d_in[3];
  const float* K3    = (const float*)d_in[4];
  float* out = (float*)d_out;
  float* ws  = (float*)d_ws;

  const size_t need = (size_t)(CTRL_FLOATS + 12*NNg) * sizeof(float);
  if (ws_size < need) {
    hipLaunchKernelGGL(diag_ws, dim3(1), dim3(1), 0, stream, out);
    return;
  }
  // zero flags + release lines + parts (harness poisons ws with 0xAA)
  hipMemsetAsync(ws, 0, CTRL_FLOATS*sizeof(float), stream);
  hipLaunchKernelGGL(drk, dim3(NBT), dim3(TPB), 0, stream,
                     U0, scale, K1, K2, K3, out, ws);
}